// Round 3
// baseline (439.925 us; speedup 1.0000x reference)
//
#include <hip/hip_runtime.h>

#define BATCH 16
#define NN 512   // n  (j index, "nxt" side; rows of X)
#define MM 512   // m  (i index, "cur" side; cols of X)
#define DD 128
#define QP_ITERS 20
#define NBLK (BATCH * 8)    // 128 qp blocks; 8 blocks per batch (64 rows each)
#define SLOT 1024           // floats per block slot (512 x-partials + 512 qx)

// ---------------------------------------------------------------------------
// gemm_q v4 (R12-proven, UNCHANGED): qm = 0.5*(rc_i + rn_j) - (nc.nn + ec.en)
// ---------------------------------------------------------------------------
__global__ __launch_bounds__(256, 2) void gemm_q_kernel(
    const float* __restrict__ nc, const float* __restrict__ ec,
    const float* __restrict__ nn, const float* __restrict__ en,
    float* __restrict__ qm, float* __restrict__ qsums,
    float* __restrict__ q2sums, unsigned* __restrict__ flags)
{
    int b  = blockIdx.z;
    int it = blockIdx.x;             // i tile, 128 wide (0..3)
    int jt = blockIdx.y;             // j tile,  64 wide (0..7)
    int tid = threadIdx.x;
    int tx = tid & 15, ty = tid >> 4;   // micro: 8 i-cols x 4 j-rows

    if (it == 0 && jt == 0 && b == 0) {          // zero qp flags (512 words)
        flags[tid] = 0u; flags[tid + 256] = 0u;
    }

    __shared__ float As[16][64];     // k-major, j rows   (4 KB)
    __shared__ float Bs[16][128];    // k-major, i rows   (8 KB)

    float acc[4][8] = {};            // [j][i]
    float s_a = 0.f, s_b = 0.f;      // row-norm partials from staged regs

    int a_row = tid & 63;            // A: 64 rows x 16k -> 1 float4/thread
    int a_kc  = (tid >> 6) * 4;      // 0,4,8,12
    int b_row = tid & 127;           // B: 128 rows x 16k -> 2 float4/thread
    int b_kc  = (tid >> 7) * 8;      // 0 or 8

    const float* aBase[2] = { nn + ((size_t)b*NN + jt*64)  * DD,
                              en + ((size_t)b*NN + jt*64)  * DD };
    const float* bBase[2] = { nc + ((size_t)b*MM + it*128) * DD,
                              ec + ((size_t)b*MM + it*128) * DD };

    float4 pa  = *(const float4*)(aBase[0] + (size_t)a_row * DD + a_kc);
    float4 pb0 = *(const float4*)(bBase[0] + (size_t)b_row * DD + b_kc);
    float4 pb1 = *(const float4*)(bBase[0] + (size_t)b_row * DD + b_kc + 4);

    for (int stage = 0; stage < 16; ++stage) {
        __syncthreads();
        As[a_kc+0][a_row] = pa.x;  As[a_kc+1][a_row] = pa.y;
        As[a_kc+2][a_row] = pa.z;  As[a_kc+3][a_row] = pa.w;
        s_a += pa.x*pa.x + pa.y*pa.y + pa.z*pa.z + pa.w*pa.w;
        Bs[b_kc+0][b_row] = pb0.x; Bs[b_kc+1][b_row] = pb0.y;
        Bs[b_kc+2][b_row] = pb0.z; Bs[b_kc+3][b_row] = pb0.w;
        Bs[b_kc+4][b_row] = pb1.x; Bs[b_kc+5][b_row] = pb1.y;
        Bs[b_kc+6][b_row] = pb1.z; Bs[b_kc+7][b_row] = pb1.w;
        s_b += pb0.x*pb0.x + pb0.y*pb0.y + pb0.z*pb0.z + pb0.w*pb0.w
             + pb1.x*pb1.x + pb1.y*pb1.y + pb1.z*pb1.z + pb1.w*pb1.w;
        __syncthreads();

        if (stage + 1 < 16) {
            int s   = stage + 1;
            int mat = s >> 3;
            int kb  = (s & 7) * 16;
            pa  = *(const float4*)(aBase[mat] + (size_t)a_row * DD + kb + a_kc);
            pb0 = *(const float4*)(bBase[mat] + (size_t)b_row * DD + kb + b_kc);
            pb1 = *(const float4*)(bBase[mat] + (size_t)b_row * DD + kb + b_kc + 4);
        }

        #pragma unroll
        for (int k = 0; k < 16; ++k) {
            float af[4], bf[8];
            *(float4*)&af[0] = *(const float4*)&As[k][ty*4];
            *(float4*)&bf[0] = *(const float4*)&Bs[k][tx*8];
            *(float4*)&bf[4] = *(const float4*)&Bs[k][tx*8+4];
            #pragma unroll
            for (int r = 0; r < 4; ++r)
                #pragma unroll
                for (int c = 0; c < 8; ++c)
                    acc[r][c] += af[r] * bf[c];
        }
    }

    // ---- combine row-norm partials through reused LDS ----
    __syncthreads();                       // k-loop LDS reads complete
    float* nA = &As[0][0];                 // 256 floats: [kchunk4][jrow64]
    float* nB = &As[4][0];                 // 256 floats: [kchunk2][irow128]
    nA[tid] = s_a;
    nB[tid] = s_b;
    __syncthreads();

    float rci[8];
    int i0 = it*128 + tx*8;
    #pragma unroll
    for (int c = 0; c < 8; ++c) {
        int il = tx*8 + c;
        rci[c] = nB[il] + nB[128 + il];    // ||nc_i||^2 + ||ec_i||^2
    }

    float qs = 0.f, q2s = 0.f;
    #pragma unroll
    for (int r = 0; r < 4; ++r) {
        int jl = ty*4 + r;
        float rnj = nA[jl] + nA[64+jl] + nA[128+jl] + nA[192+jl];
        int j = jt*64 + jl;
        size_t rowp = ((size_t)b*NN + j)*MM + i0;
        float4 o0, o1;
        float v;
        v = 0.5f*(rci[0] + rnj) - acc[r][0]; o0.x = v; qs += v; q2s += v*v;
        v = 0.5f*(rci[1] + rnj) - acc[r][1]; o0.y = v; qs += v; q2s += v*v;
        v = 0.5f*(rci[2] + rnj) - acc[r][2]; o0.z = v; qs += v; q2s += v*v;
        v = 0.5f*(rci[3] + rnj) - acc[r][3]; o0.w = v; qs += v; q2s += v*v;
        v = 0.5f*(rci[4] + rnj) - acc[r][4]; o1.x = v; qs += v; q2s += v*v;
        v = 0.5f*(rci[5] + rnj) - acc[r][5]; o1.y = v; qs += v; q2s += v*v;
        v = 0.5f*(rci[6] + rnj) - acc[r][6]; o1.z = v; qs += v; q2s += v*v;
        v = 0.5f*(rci[7] + rnj) - acc[r][7]; o1.w = v; qs += v; q2s += v*v;
        *(float4*)(qm + rowp)     = o0;
        *(float4*)(qm + rowp + 4) = o1;
    }

    #pragma unroll
    for (int off = 32; off; off >>= 1) {
        qs  += __shfl_down(qs,  off);
        q2s += __shfl_down(q2s, off);
    }
    __shared__ float red[8];
    int wid = tid >> 6, lane = tid & 63;
    if (lane == 0) { red[wid] = qs; red[4 + wid] = q2s; }
    __syncthreads();
    if (tid == 0) {
        int tile = b * 32 + jt * 4 + it;
        qsums[tile]  = red[0] + red[1] + red[2] + red[3];
        q2sums[tile] = red[4] + red[5] + red[6] + red[7];
    }
}

// ---------------------------------------------------------------------------
__device__ __forceinline__ float gather8_sum_agent(const float* p)
{
    float acc = 0.f;
    #pragma unroll
    for (int g2 = 0; g2 < 8; ++g2)
        acc += __hip_atomic_load((float*)(p + g2 * SLOT), __ATOMIC_RELAXED,
                                 __HIP_MEMORY_SCOPE_AGENT);
    return acc;
}

// ---------------------------------------------------------------------------
// qp_iter_kernel v11: R9/R10-proven sync protocol, fan-in halved.
// 8 blocks per batch x 64 rows; each thread owns TWO row-halves
// (r0 = tid>>5, r1 = r0+32) with the SAME cseg (tid&31), so the wave
// geometry, 66 KB LDS layout, shuffle patterns, and flag protocol are
// unchanged from the proven 16-block version. Column partials combine the
// two halves before the xor(32) pair-sum: one shfl per array per k, same
// as before. 128 blocks x 1024 thr, VGPR capped at 128 by launch_bounds
// (q 32 + x 32 + fk 16 + temps ~ 110) -> 1 block/CU, 128 <= 256 CUs:
// all blocks co-resident by construction.
// ---------------------------------------------------------------------------
__global__ __launch_bounds__(1024, 4) void qp_iter_kernel(
    const float* __restrict__ qm, const float* __restrict__ qsums,
    const float* __restrict__ q2sums, float* __restrict__ part,
    unsigned* __restrict__ flags, float* __restrict__ out)
{
    __shared__ float lds[16384 + 32];        // partial matrices + wred
    __shared__ int sh_ok;
    float* stage = lds;                      // [1024]: 0..511 f, 512..1023 colq
    float* wred  = lds + 16384;              // [16] wave partials for s

    int tid   = threadIdx.x;
    int blk   = blockIdx.x;
    int b     = blk >> 3;            // batch
    int g     = blk & 7;             // row-group: rows g*64..g*64+63
    int w     = tid >> 6;            // wave 0..15
    int lane  = tid & 63;
    int r_loc = tid >> 5;            // 0..31 local row (first half)
    int cseg  = tid & 31;            // owns cols cseg + 32k
    int j0    = g * 64 + r_loc;      // first-half row
    // second-half row = j0 + 32

    size_t rowbase0 = ((size_t)b * NN + j0) * MM;
    size_t rowbase1 = rowbase0 + (size_t)32 * MM;

    // ---- prologue: reduce 32 per-tile sums -> lr, s1 ----
    if (w == 0) {
        float v1 = (lane < 32) ? qsums[b * 32 + lane]  : 0.f;
        float v2 = (lane < 32) ? q2sums[b * 32 + lane] : 0.f;
        #pragma unroll
        for (int m = 32; m; m >>= 1) {
            v1 += __shfl_xor(v1, m);
            v2 += __shfl_xor(v2, m);
        }
        if (lane == 0) { wred[0] = v1; wred[1] = v2; }
    }

    float q0[16], q1[16], x0[16], x1[16], fk[16];
    #pragma unroll
    for (int k = 0; k < 16; ++k) {
        q0[k] = qm[rowbase0 + cseg + 32*k];
        q1[k] = qm[rowbase1 + cseg + 32*k];
    }

    const float inv_m = 1.0f / (float)MM;
    #pragma unroll
    for (int k = 0; k < 16; ++k) { x0[k] = inv_m; x1[k] = inv_m; fk[k] = 1.0f; }

    __syncthreads();
    const float lr = 0.5f / (wred[1] + 1e-8f);
    float s = wred[0] * inv_m;       // s1 = sum(qm)/m  (X0 = 1/m)

    unsigned* myflag = flags + b * 8 + g;
    unsigned* bflags = flags + b * 8;

    for (int t = 1; t <= QP_ITERS; ++t) {
        if (t > 1) {
            unsigned tt = (unsigned)(t - 1);
            // ---- speculative probe (acquire) ----
            if (w == 0) {
                unsigned v = (lane < 8)
                    ? __hip_atomic_load(bflags + lane, __ATOMIC_ACQUIRE,
                                        __HIP_MEMORY_SCOPE_AGENT)
                    : tt;
                int ok = __all(v >= tt);
                if (lane == 0) sh_ok = ok;
            }
            __syncthreads();   // broadcast sh_ok; prior lds reads all done

            const float* p = part + (size_t)((t - 1) & 1) * (NBLK * SLOT)
                           + (size_t)b * (8 * SLOT) + tid;
            float acc = gather8_sum_agent(p);

            if (!sh_ok) {      // fallback: proven poll + ordered re-gather
                if (w == 0) {
                    for (;;) {
                        unsigned v = (lane < 8)
                            ? __hip_atomic_load(bflags + lane, __ATOMIC_ACQUIRE,
                                                __HIP_MEMORY_SCOPE_AGENT)
                            : tt;
                        if (__all(v >= tt)) break;
                    }
                }
                __syncthreads();
                acc = gather8_sum_agent(p);
            }

            if (tid < 512) stage[tid] = fminf(1.0f, 2.0f / (acc + 1e-8f)); // f
            else           stage[tid] = acc;                               // colq
            __syncthreads();
            float v = (tid < 512) ? stage[tid] * stage[512 + tid] : 0.f;
            #pragma unroll
            for (int m = 32; m; m >>= 1) v += __shfl_xor(v, m);
            if (lane == 0) wred[w] = v;
            #pragma unroll
            for (int k = 0; k < 16; ++k) fk[k] = stage[cseg + 32*k];
            __syncthreads();   // wred ready; all stage reads complete
            float sacc = 0.f;
            #pragma unroll
            for (int i = 0; i < 16; ++i) sacc += wred[i];   // LDS broadcast
            s = sacc;
        }

        // ---- gradient step + clip + row normalize (both row-halves) ----
        float c = 2.0f * lr * s;
        float rp0 = 0.f, rp1 = 0.f;
        #pragma unroll
        for (int k = 0; k < 16; ++k) {
            float v0 = x0[k] * fk[k] - c * q0[k];
            v0 = fminf(fmaxf(v0, 0.f), 1.f);
            x0[k] = v0; rp0 += v0;
            float v1 = x1[k] * fk[k] - c * q1[k];
            v1 = fminf(fmaxf(v1, 0.f), 1.f);
            x1[k] = v1; rp1 += v1;
        }
        #pragma unroll
        for (int m = 16; m; m >>= 1) {
            rp0 += __shfl_xor(rp0, m);
            rp1 += __shfl_xor(rp1, m);
        }
        float inv0 = 1.0f / (rp0 + 1e-8f);
        float inv1 = 1.0f / (rp1 + 1e-8f);
        #pragma unroll
        for (int k = 0; k < 16; ++k) { x0[k] *= inv0; x1[k] *= inv1; }

        // ---- column partial pass (4 rows per wave via half-sum + xor32) ----
        #pragma unroll
        for (int k = 0; k < 16; ++k) {
            float sx = x0[k] + x1[k];                    // rows r0 and r0+32
            float sq = q0[k] * x0[k] + q1[k] * x1[k];
            float px = sx + __shfl_xor(sx, 32);          // + partner rows
            float pq = sq + __shfl_xor(sq, 32);
            int col = cseg + 32*k;
            if (lane < 32) lds[w * 512 + col]        = px;   // x partials
            else           lds[8192 + w * 512 + col] = pq;   // qx partials
        }
        __syncthreads();
        {
            int arr = tid >> 9;          // 0 => colsum(x), 1 => colsum(qx)
            int col = tid & 511;
            const float* basep = lds + arr * 8192 + col;
            float acc = 0.f;
            #pragma unroll
            for (int w2 = 0; w2 < 16; ++w2) acc += basep[w2 * 512];
            float* dst = part + (size_t)(t & 1) * (NBLK * SLOT)
                       + (size_t)blk * SLOT + tid;
            __hip_atomic_store(dst, acc, __ATOMIC_RELAXED,
                               __HIP_MEMORY_SCOPE_AGENT);
        }

        __syncthreads();   // drain every thread's partial store (vmcnt 0)
        if (tid == 0)
            __hip_atomic_store(myflag, (unsigned)t, __ATOMIC_RELEASE,
                               __HIP_MEMORY_SCOPE_AGENT);
    }

    // ---- final: poll iteration 20's flags, gather colsum, scale, store ----
    {
        unsigned tt = (unsigned)QP_ITERS;
        if (w == 0) {
            for (;;) {
                unsigned v = (lane < 8)
                    ? __hip_atomic_load(bflags + lane, __ATOMIC_ACQUIRE,
                                        __HIP_MEMORY_SCOPE_AGENT)
                    : tt;
                if (__all(v >= tt)) break;
            }
        }
        __syncthreads();
        const float* p = part + (size_t)(QP_ITERS & 1) * (NBLK * SLOT)
                       + (size_t)b * (8 * SLOT) + tid;   // tid<512: x-partials
        if (tid < 512) {
            float acc = gather8_sum_agent(p);
            stage[tid] = fminf(1.0f, 2.0f / (acc + 1e-8f));
        }
        __syncthreads();
        #pragma unroll
        for (int k = 0; k < 16; ++k) {
            float f = stage[cseg + 32*k];
            out[rowbase0 + cseg + 32*k] = x0[k] * f;
            out[rowbase1 + cseg + 32*k] = x1[k] * f;
        }
    }
}

// ---------------------------------------------------------------------------
extern "C" void kernel_launch(void* const* d_in, const int* in_sizes, int n_in,
                              void* d_out, int out_size, void* d_ws, size_t ws_size,
                              hipStream_t stream)
{
    const float* nc = (const float*)d_in[0];  // n_emb_cur (16,512,128)
    const float* ec = (const float*)d_in[1];  // e_emb_cur
    const float* nn = (const float*)d_in[2];  // n_emb_nxt
    const float* en = (const float*)d_in[3];  // e_emb_nxt
    float* out = (float*)d_out;               // (16, 512*512) fp32

    float* ws = (float*)d_ws;
    const size_t QM_FLOATS = (size_t)BATCH * NN * MM;       // 4,194,304 (16 MB)

    float* qm   = ws;
    float* part = ws + QM_FLOATS;                           // 2*NBLK*SLOT floats
    float* qsums  = part + (size_t)2 * NBLK * SLOT;         // 512
    float* q2sums = qsums + 512;                            // 512
    unsigned* flags = (unsigned*)(q2sums + 512);            // 512 words (128 used)

    gemm_q_kernel<<<dim3(4, 8, BATCH), 256, 0, stream>>>(nc, ec, nn, en, qm,
                                                         qsums, q2sums, flags);

    // NORMAL launch: 128 blocks x 16 waves, VGPR<=128 -> 1 block/CU capacity
    // (256) >= 128, so all blocks are co-resident by construction; all
    // inter-block sync is hand-rolled flag spins.
    qp_iter_kernel<<<dim3(NBLK), dim3(1024), 0, stream>>>(
        qm, qsums, q2sums, part, flags, out);
}

// Round 4
// 324.516 us; speedup vs baseline: 1.3556x; 1.3556x over previous
//
#include <hip/hip_runtime.h>

#define BATCH 16
#define NN 512   // n  (j index, "nxt" side; rows of X)
#define MM 512   // m  (i index, "cur" side; cols of X)
#define DD 128
#define QP_ITERS 20
#define NBLK (BATCH * 16)   // 256 qp blocks; 2-blocks/CU capacity => all resident
#define SLOT 1024           // floats per block slot (512 x-partials + 512 qx)

// ---------------------------------------------------------------------------
// gemm_q v5: same math/tiling as proven v4 (128i x 64j tile, BK=16, k-major
// LDS, 4x8 micro) but software-pipelined: double-buffered LDS (24 KB),
// 2-stage register prefetch, ONE barrier per stage (16 vs 32). FMA order
// per k unchanged -> bitwise-identical qm vs v4.
// ---------------------------------------------------------------------------

#define LOAD_STAGE(PA, PB0, PB1, s)                                           \
    PA  = *(const float4*)(aBase[(s)>>3] + (size_t)a_row*DD + ((s)&7)*16 + a_kc);   \
    PB0 = *(const float4*)(bBase[(s)>>3] + (size_t)b_row*DD + ((s)&7)*16 + b_kc);   \
    PB1 = *(const float4*)(bBase[(s)>>3] + (size_t)b_row*DD + ((s)&7)*16 + b_kc + 4);

#define STORE_STAGE(buf, PA, PB0, PB1)                                        \
    As[buf][a_kc+0][a_row] = PA.x;  As[buf][a_kc+1][a_row] = PA.y;            \
    As[buf][a_kc+2][a_row] = PA.z;  As[buf][a_kc+3][a_row] = PA.w;            \
    s_a += PA.x*PA.x + PA.y*PA.y + PA.z*PA.z + PA.w*PA.w;                     \
    Bs[buf][b_kc+0][b_row] = PB0.x; Bs[buf][b_kc+1][b_row] = PB0.y;           \
    Bs[buf][b_kc+2][b_row] = PB0.z; Bs[buf][b_kc+3][b_row] = PB0.w;           \
    Bs[buf][b_kc+4][b_row] = PB1.x; Bs[buf][b_kc+5][b_row] = PB1.y;           \
    Bs[buf][b_kc+6][b_row] = PB1.z; Bs[buf][b_kc+7][b_row] = PB1.w;           \
    s_b += PB0.x*PB0.x + PB0.y*PB0.y + PB0.z*PB0.z + PB0.w*PB0.w              \
         + PB1.x*PB1.x + PB1.y*PB1.y + PB1.z*PB1.z + PB1.w*PB1.w;

#define COMPUTE_STAGE(buf)                                                    \
    _Pragma("unroll")                                                         \
    for (int k = 0; k < 16; ++k) {                                            \
        float af[4], bf[8];                                                   \
        *(float4*)&af[0] = *(const float4*)&As[buf][k][ty*4];                 \
        *(float4*)&bf[0] = *(const float4*)&Bs[buf][k][tx*8];                 \
        *(float4*)&bf[4] = *(const float4*)&Bs[buf][k][tx*8+4];               \
        _Pragma("unroll")                                                     \
        for (int r = 0; r < 4; ++r)                                           \
            _Pragma("unroll")                                                 \
            for (int c = 0; c < 8; ++c)                                       \
                acc[r][c] += af[r] * bf[c];                                   \
    }

__global__ __launch_bounds__(256, 2) void gemm_q_kernel(
    const float* __restrict__ nc, const float* __restrict__ ec,
    const float* __restrict__ nn, const float* __restrict__ en,
    float* __restrict__ qm, float* __restrict__ qsums,
    float* __restrict__ q2sums, unsigned* __restrict__ flags)
{
    int b  = blockIdx.z;
    int it = blockIdx.x;             // i tile, 128 wide (0..3)
    int jt = blockIdx.y;             // j tile,  64 wide (0..7)
    int tid = threadIdx.x;
    int tx = tid & 15, ty = tid >> 4;   // micro: 8 i-cols x 4 j-rows

    if (it == 0 && jt == 0 && b == 0) {          // zero qp flags (512 words)
        flags[tid] = 0u; flags[tid + 256] = 0u;
    }

    __shared__ float As[2][16][64];   // double-buffered, k-major, j rows (8 KB)
    __shared__ float Bs[2][16][128];  // double-buffered, k-major, i rows (16 KB)

    float acc[4][8] = {};            // [j][i]
    float s_a = 0.f, s_b = 0.f;      // row-norm partials from staged regs

    int a_row = tid & 63;            // A: 64 rows x 16k -> 1 float4/thread
    int a_kc  = (tid >> 6) * 4;      // 0,4,8,12
    int b_row = tid & 127;           // B: 128 rows x 16k -> 2 float4/thread
    int b_kc  = (tid >> 7) * 8;      // 0 or 8

    const float* aBase[2] = { nn + ((size_t)b*NN + jt*64)  * DD,
                              en + ((size_t)b*NN + jt*64)  * DD };
    const float* bBase[2] = { nc + ((size_t)b*MM + it*128) * DD,
                              ec + ((size_t)b*MM + it*128) * DD };

    float4 pa0, pb00, pb10;          // register set 0: even stages
    float4 pa1, pb01, pb11;          // register set 1: odd stages

    LOAD_STAGE(pa0, pb00, pb10, 0);
    LOAD_STAGE(pa1, pb01, pb11, 1);
    STORE_STAGE(0, pa0, pb00, pb10);          // stage 0 -> LDS[0]

    // Pipeline invariant at top of pair sp (s0=2sp, s1=2sp+1):
    //   LDS[0] holds stage s0 (stored last half-iter / prologue)
    //   set1 holds stage s1's registers
    #pragma unroll
    for (int sp = 0; sp < 8; ++sp) {
        const int s0 = 2*sp, s1 = 2*sp + 1;
        __syncthreads();                       // LDS[1] readers (s0-1) done;
                                               // LDS[0] stores visible
        STORE_STAGE(1, pa1, pb01, pb11);       // stage s1 -> LDS[1]
        if (s0 + 2 < 16) { LOAD_STAGE(pa0, pb00, pb10, s0 + 2); }
        COMPUTE_STAGE(0);                      // stage s0
        __syncthreads();                       // LDS[0] readers done;
                                               // LDS[1] stores visible
        if (s1 + 1 < 16) { STORE_STAGE(0, pa0, pb00, pb10); }   // stage s0+2
        if (s1 + 2 < 16) { LOAD_STAGE(pa1, pb01, pb11, s1 + 2); }
        COMPUTE_STAGE(1);                      // stage s1
    }

    // ---- combine row-norm partials through reused LDS ----
    __syncthreads();                       // k-loop LDS reads complete
    float* nA = &As[0][0][0];              // 256 floats: [kchunk4][jrow64]
    float* nB = &As[0][4][0];              // 256 floats: [kchunk2][irow128]
    nA[tid] = s_a;
    nB[tid] = s_b;
    __syncthreads();

    float rci[8];
    int i0 = it*128 + tx*8;
    #pragma unroll
    for (int c = 0; c < 8; ++c) {
        int il = tx*8 + c;
        rci[c] = nB[il] + nB[128 + il];    // ||nc_i||^2 + ||ec_i||^2
    }

    float qs = 0.f, q2s = 0.f;
    #pragma unroll
    for (int r = 0; r < 4; ++r) {
        int jl = ty*4 + r;
        float rnj = nA[jl] + nA[64+jl] + nA[128+jl] + nA[192+jl];
        int j = jt*64 + jl;
        size_t rowp = ((size_t)b*NN + j)*MM + i0;
        float4 o0, o1;
        float v;
        v = 0.5f*(rci[0] + rnj) - acc[r][0]; o0.x = v; qs += v; q2s += v*v;
        v = 0.5f*(rci[1] + rnj) - acc[r][1]; o0.y = v; qs += v; q2s += v*v;
        v = 0.5f*(rci[2] + rnj) - acc[r][2]; o0.z = v; qs += v; q2s += v*v;
        v = 0.5f*(rci[3] + rnj) - acc[r][3]; o0.w = v; qs += v; q2s += v*v;
        v = 0.5f*(rci[4] + rnj) - acc[r][4]; o1.x = v; qs += v; q2s += v*v;
        v = 0.5f*(rci[5] + rnj) - acc[r][5]; o1.y = v; qs += v; q2s += v*v;
        v = 0.5f*(rci[6] + rnj) - acc[r][6]; o1.z = v; qs += v; q2s += v*v;
        v = 0.5f*(rci[7] + rnj) - acc[r][7]; o1.w = v; qs += v; q2s += v*v;
        *(float4*)(qm + rowp)     = o0;
        *(float4*)(qm + rowp + 4) = o1;
    }

    #pragma unroll
    for (int off = 32; off; off >>= 1) {
        qs  += __shfl_down(qs,  off);
        q2s += __shfl_down(q2s, off);
    }
    __shared__ float red[8];
    int wid = tid >> 6, lane = tid & 63;
    if (lane == 0) { red[wid] = qs; red[4 + wid] = q2s; }
    __syncthreads();
    if (tid == 0) {
        int tile = b * 32 + jt * 4 + it;
        qsums[tile]  = red[0] + red[1] + red[2] + red[3];
        q2sums[tile] = red[4] + red[5] + red[6] + red[7];
    }
}

// ---------------------------------------------------------------------------
__device__ __forceinline__ float gather16_sum_agent(const float* p)
{
    float acc = 0.f;
    #pragma unroll
    for (int g2 = 0; g2 < 16; ++g2)
        acc += __hip_atomic_load((float*)(p + g2 * SLOT), __ATOMIC_RELAXED,
                                 __HIP_MEMORY_SCOPE_AGENT);
    return acc;
}

// ---------------------------------------------------------------------------
// qp_iter_kernel v10 (REVERTED to proven 237 us / 56 VGPR version; the v11
// fan-in-8 variant spilled ~20 regs/thread -> WRITE_SIZE 37->291 MB, +46%).
// ---------------------------------------------------------------------------
__global__ __launch_bounds__(1024, 4) void qp_iter_kernel(
    const float* __restrict__ qm, const float* __restrict__ qsums,
    const float* __restrict__ q2sums, float* __restrict__ part,
    unsigned* __restrict__ flags, float* __restrict__ out)
{
    __shared__ float lds[16384 + 32];        // partial matrices + wred
    __shared__ int sh_ok;
    float* stage = lds;                      // [1024]: 0..511 f, 512..1023 colq
    float* wred  = lds + 16384;              // [16] wave partials for s

    int tid   = threadIdx.x;
    int blk   = blockIdx.x;
    int b     = blk >> 4;            // batch
    int g     = blk & 15;            // row-group: rows g*32..g*32+31
    int w     = tid >> 6;            // wave 0..15
    int lane  = tid & 63;
    int r_loc = tid >> 5;            // 0..31 local row
    int cseg  = tid & 31;            // owns cols cseg + 32k
    int j     = g * 32 + r_loc;

    size_t rowbase = ((size_t)b * NN + j) * MM;

    // ---- prologue: reduce 32 per-tile sums -> lr, s1 ----
    if (w == 0) {
        float v1 = (lane < 32) ? qsums[b * 32 + lane]  : 0.f;
        float v2 = (lane < 32) ? q2sums[b * 32 + lane] : 0.f;
        #pragma unroll
        for (int m = 32; m; m >>= 1) {
            v1 += __shfl_xor(v1, m);
            v2 += __shfl_xor(v2, m);
        }
        if (lane == 0) { wred[0] = v1; wred[1] = v2; }
    }

    float q[16], x[16], fk[16];
    #pragma unroll
    for (int k = 0; k < 16; ++k) q[k] = qm[rowbase + cseg + 32*k];

    const float inv_m = 1.0f / (float)MM;
    #pragma unroll
    for (int k = 0; k < 16; ++k) { x[k] = inv_m; fk[k] = 1.0f; }

    __syncthreads();
    const float lr = 0.5f / (wred[1] + 1e-8f);
    float s = wred[0] * inv_m;       // s1 = sum(qm)/m  (X0 = 1/m)

    unsigned* myflag = flags + b * 32 + g;
    unsigned* bflags = flags + b * 32;

    for (int t = 1; t <= QP_ITERS; ++t) {
        if (t > 1) {
            unsigned tt = (unsigned)(t - 1);
            // ---- speculative probe (acquire) ----
            if (w == 0) {
                unsigned v = (lane < 16)
                    ? __hip_atomic_load(bflags + lane, __ATOMIC_ACQUIRE,
                                        __HIP_MEMORY_SCOPE_AGENT)
                    : tt;
                int ok = __all(v >= tt);
                if (lane == 0) sh_ok = ok;
            }
            __syncthreads();   // broadcast sh_ok; prior lds reads all done

            const float* p = part + (size_t)((t - 1) & 1) * (NBLK * SLOT)
                           + (size_t)b * (16 * SLOT) + tid;
            float acc = gather16_sum_agent(p);

            if (!sh_ok) {      // fallback: proven poll + ordered re-gather
                if (w == 0) {
                    for (;;) {
                        unsigned v = (lane < 16)
                            ? __hip_atomic_load(bflags + lane, __ATOMIC_ACQUIRE,
                                                __HIP_MEMORY_SCOPE_AGENT)
                            : tt;
                        if (__all(v >= tt)) break;
                    }
                }
                __syncthreads();
                acc = gather16_sum_agent(p);
            }

            if (tid < 512) stage[tid] = fminf(1.0f, 2.0f / (acc + 1e-8f)); // f
            else           stage[tid] = acc;                               // colq
            __syncthreads();
            float v = (tid < 512) ? stage[tid] * stage[512 + tid] : 0.f;
            #pragma unroll
            for (int m = 32; m; m >>= 1) v += __shfl_xor(v, m);
            if (lane == 0) wred[w] = v;
            #pragma unroll
            for (int k = 0; k < 16; ++k) fk[k] = stage[cseg + 32*k];
            __syncthreads();   // wred ready; all stage reads complete
            float sacc = 0.f;
            #pragma unroll
            for (int i = 0; i < 16; ++i) sacc += wred[i];   // LDS broadcast
            s = sacc;
        }

        // ---- gradient step + clip + row normalize ----
        float c = 2.0f * lr * s;
        float rp = 0.f;
        #pragma unroll
        for (int k = 0; k < 16; ++k) {
            float v = x[k] * fk[k] - c * q[k];
            v = fminf(fmaxf(v, 0.f), 1.f);
            x[k] = v;
            rp += v;
        }
        #pragma unroll
        for (int m = 16; m; m >>= 1) rp += __shfl_xor(rp, m);
        float inv = 1.0f / (rp + 1e-8f);
        #pragma unroll
        for (int k = 0; k < 16; ++k) x[k] *= inv;

        // ---- column partial pass ----
        #pragma unroll
        for (int k = 0; k < 16; ++k) {
            float qx = q[k] * x[k];
            float px = x[k] + __shfl_xor(x[k], 32);   // row-pair sum
            float pq = qx   + __shfl_xor(qx,   32);
            int col = cseg + 32*k;
            if (lane < 32) lds[w * 512 + col]        = px;   // x partials
            else           lds[8192 + w * 512 + col] = pq;   // qx partials
        }
        __syncthreads();
        {
            int arr = tid >> 9;          // 0 => colsum(x), 1 => colsum(qx)
            int col = tid & 511;
            const float* basep = lds + arr * 8192 + col;
            float acc = 0.f;
            #pragma unroll
            for (int w2 = 0; w2 < 16; ++w2) acc += basep[w2 * 512];
            float* dst = part + (size_t)(t & 1) * (NBLK * SLOT)
                       + (size_t)blk * SLOT + tid;
            __hip_atomic_store(dst, acc, __ATOMIC_RELAXED,
                               __HIP_MEMORY_SCOPE_AGENT);
        }

        __syncthreads();   // drain every thread's partial store (vmcnt 0)
        if (tid == 0)
            __hip_atomic_store(myflag, (unsigned)t, __ATOMIC_RELEASE,
                               __HIP_MEMORY_SCOPE_AGENT);
    }

    // ---- final: poll iteration 20's flags, gather colsum, scale, store ----
    {
        unsigned tt = (unsigned)QP_ITERS;
        if (w == 0) {
            for (;;) {
                unsigned v = (lane < 16)
                    ? __hip_atomic_load(bflags + lane, __ATOMIC_ACQUIRE,
                                        __HIP_MEMORY_SCOPE_AGENT)
                    : tt;
                if (__all(v >= tt)) break;
            }
        }
        __syncthreads();
        const float* p = part + (size_t)(QP_ITERS & 1) * (NBLK * SLOT)
                       + (size_t)b * (16 * SLOT) + tid;   // tid<512: x-partials
        if (tid < 512) {
            float acc = gather16_sum_agent(p);
            stage[tid] = fminf(1.0f, 2.0f / (acc + 1e-8f));
        }
        __syncthreads();
        #pragma unroll
        for (int k = 0; k < 16; ++k)
            out[rowbase + cseg + 32*k] = x[k] * stage[cseg + 32*k];
    }
}

// ---------------------------------------------------------------------------
extern "C" void kernel_launch(void* const* d_in, const int* in_sizes, int n_in,
                              void* d_out, int out_size, void* d_ws, size_t ws_size,
                              hipStream_t stream)
{
    const float* nc = (const float*)d_in[0];  // n_emb_cur (16,512,128)
    const float* ec = (const float*)d_in[1];  // e_emb_cur
    const float* nn = (const float*)d_in[2];  // n_emb_nxt
    const float* en = (const float*)d_in[3];  // e_emb_nxt
    float* out = (float*)d_out;               // (16, 512*512) fp32

    float* ws = (float*)d_ws;
    const size_t QM_FLOATS = (size_t)BATCH * NN * MM;       // 4,194,304 (16 MB)

    float* qm   = ws;
    float* part = ws + QM_FLOATS;                           // 2*NBLK*SLOT floats
    float* qsums  = part + (size_t)2 * NBLK * SLOT;         // 512
    float* q2sums = qsums + 512;                            // 512
    unsigned* flags = (unsigned*)(q2sums + 512);            // 512 words

    gemm_q_kernel<<<dim3(4, 8, BATCH), 256, 0, stream>>>(nc, ec, nn, en, qm,
                                                         qsums, q2sums, flags);

    // NORMAL launch: capacity (2 blocks/CU x 256 CUs) >= 256 blocks ensures
    // co-residency; all inter-block sync is hand-rolled flag spins.
    qp_iter_kernel<<<dim3(NBLK), dim3(1024), 0, stream>>>(
        qm, qsums, q2sums, part, flags, out);
}

// Round 5
// 264.816 us; speedup vs baseline: 1.6612x; 1.2254x over previous
//
#include <hip/hip_runtime.h>

#define BATCH 16
#define NN 512   // n  (j index, "nxt" side; rows of X)
#define MM 512   // m  (i index, "cur" side; cols of X)
#define DD 128
#define QP_ITERS 20
#define NBLK (BATCH * 16)   // 256 qp blocks; 2-blocks/CU capacity => all resident
#define SLOT 1024           // floats per block slot (512 x-partials + 512 qx)

// ---------------------------------------------------------------------------
// gemm_q v5 (R4-measured neutral vs v4; kept): 128i x 64j tile, BK=16,
// k-major LDS, 4x8 micro, double-buffered LDS, one barrier per stage.
// ---------------------------------------------------------------------------

#define LOAD_STAGE(PA, PB0, PB1, s)                                           \
    PA  = *(const float4*)(aBase[(s)>>3] + (size_t)a_row*DD + ((s)&7)*16 + a_kc);   \
    PB0 = *(const float4*)(bBase[(s)>>3] + (size_t)b_row*DD + ((s)&7)*16 + b_kc);   \
    PB1 = *(const float4*)(bBase[(s)>>3] + (size_t)b_row*DD + ((s)&7)*16 + b_kc + 4);

#define STORE_STAGE(buf, PA, PB0, PB1)                                        \
    As[buf][a_kc+0][a_row] = PA.x;  As[buf][a_kc+1][a_row] = PA.y;            \
    As[buf][a_kc+2][a_row] = PA.z;  As[buf][a_kc+3][a_row] = PA.w;            \
    s_a += PA.x*PA.x + PA.y*PA.y + PA.z*PA.z + PA.w*PA.w;                     \
    Bs[buf][b_kc+0][b_row] = PB0.x; Bs[buf][b_kc+1][b_row] = PB0.y;           \
    Bs[buf][b_kc+2][b_row] = PB0.z; Bs[buf][b_kc+3][b_row] = PB0.w;           \
    Bs[buf][b_kc+4][b_row] = PB1.x; Bs[buf][b_kc+5][b_row] = PB1.y;           \
    Bs[buf][b_kc+6][b_row] = PB1.z; Bs[buf][b_kc+7][b_row] = PB1.w;           \
    s_b += PB0.x*PB0.x + PB0.y*PB0.y + PB0.z*PB0.z + PB0.w*PB0.w              \
         + PB1.x*PB1.x + PB1.y*PB1.y + PB1.z*PB1.z + PB1.w*PB1.w;

#define COMPUTE_STAGE(buf)                                                    \
    _Pragma("unroll")                                                         \
    for (int k = 0; k < 16; ++k) {                                            \
        float af[4], bf[8];                                                   \
        *(float4*)&af[0] = *(const float4*)&As[buf][k][ty*4];                 \
        *(float4*)&bf[0] = *(const float4*)&Bs[buf][k][tx*8];                 \
        *(float4*)&bf[4] = *(const float4*)&Bs[buf][k][tx*8+4];               \
        _Pragma("unroll")                                                     \
        for (int r = 0; r < 4; ++r)                                           \
            _Pragma("unroll")                                                 \
            for (int c = 0; c < 8; ++c)                                       \
                acc[r][c] += af[r] * bf[c];                                   \
    }

__global__ __launch_bounds__(256, 2) void gemm_q_kernel(
    const float* __restrict__ nc, const float* __restrict__ ec,
    const float* __restrict__ nn, const float* __restrict__ en,
    float* __restrict__ qm, float* __restrict__ qsums,
    float* __restrict__ q2sums, unsigned* __restrict__ flags)
{
    int b  = blockIdx.z;
    int it = blockIdx.x;             // i tile, 128 wide (0..3)
    int jt = blockIdx.y;             // j tile,  64 wide (0..7)
    int tid = threadIdx.x;
    int tx = tid & 15, ty = tid >> 4;   // micro: 8 i-cols x 4 j-rows

    if (it == 0 && jt == 0 && b == 0) {          // zero qp flags (512 words)
        flags[tid] = 0u; flags[tid + 256] = 0u;
    }

    __shared__ float As[2][16][64];   // double-buffered, k-major, j rows (8 KB)
    __shared__ float Bs[2][16][128];  // double-buffered, k-major, i rows (16 KB)

    float acc[4][8] = {};            // [j][i]
    float s_a = 0.f, s_b = 0.f;      // row-norm partials from staged regs

    int a_row = tid & 63;            // A: 64 rows x 16k -> 1 float4/thread
    int a_kc  = (tid >> 6) * 4;      // 0,4,8,12
    int b_row = tid & 127;           // B: 128 rows x 16k -> 2 float4/thread
    int b_kc  = (tid >> 7) * 8;      // 0 or 8

    const float* aBase[2] = { nn + ((size_t)b*NN + jt*64)  * DD,
                              en + ((size_t)b*NN + jt*64)  * DD };
    const float* bBase[2] = { nc + ((size_t)b*MM + it*128) * DD,
                              ec + ((size_t)b*MM + it*128) * DD };

    float4 pa0, pb00, pb10;          // register set 0: even stages
    float4 pa1, pb01, pb11;          // register set 1: odd stages

    LOAD_STAGE(pa0, pb00, pb10, 0);
    LOAD_STAGE(pa1, pb01, pb11, 1);
    STORE_STAGE(0, pa0, pb00, pb10);          // stage 0 -> LDS[0]

    #pragma unroll
    for (int sp = 0; sp < 8; ++sp) {
        const int s0 = 2*sp, s1 = 2*sp + 1;
        __syncthreads();                       // LDS[1] readers (s0-1) done;
                                               // LDS[0] stores visible
        STORE_STAGE(1, pa1, pb01, pb11);       // stage s1 -> LDS[1]
        if (s0 + 2 < 16) { LOAD_STAGE(pa0, pb00, pb10, s0 + 2); }
        COMPUTE_STAGE(0);                      // stage s0
        __syncthreads();                       // LDS[0] readers done;
                                               // LDS[1] stores visible
        if (s1 + 1 < 16) { STORE_STAGE(0, pa0, pb00, pb10); }   // stage s0+2
        if (s1 + 2 < 16) { LOAD_STAGE(pa1, pb01, pb11, s1 + 2); }
        COMPUTE_STAGE(1);                      // stage s1
    }

    // ---- combine row-norm partials through reused LDS ----
    __syncthreads();                       // k-loop LDS reads complete
    float* nA = &As[0][0][0];              // 256 floats: [kchunk4][jrow64]
    float* nB = &As[0][4][0];              // 256 floats: [kchunk2][irow128]
    nA[tid] = s_a;
    nB[tid] = s_b;
    __syncthreads();

    float rci[8];
    int i0 = it*128 + tx*8;
    #pragma unroll
    for (int c = 0; c < 8; ++c) {
        int il = tx*8 + c;
        rci[c] = nB[il] + nB[128 + il];    // ||nc_i||^2 + ||ec_i||^2
    }

    float qs = 0.f, q2s = 0.f;
    #pragma unroll
    for (int r = 0; r < 4; ++r) {
        int jl = ty*4 + r;
        float rnj = nA[jl] + nA[64+jl] + nA[128+jl] + nA[192+jl];
        int j = jt*64 + jl;
        size_t rowp = ((size_t)b*NN + j)*MM + i0;
        float4 o0, o1;
        float v;
        v = 0.5f*(rci[0] + rnj) - acc[r][0]; o0.x = v; qs += v; q2s += v*v;
        v = 0.5f*(rci[1] + rnj) - acc[r][1]; o0.y = v; qs += v; q2s += v*v;
        v = 0.5f*(rci[2] + rnj) - acc[r][2]; o0.z = v; qs += v; q2s += v*v;
        v = 0.5f*(rci[3] + rnj) - acc[r][3]; o0.w = v; qs += v; q2s += v*v;
        v = 0.5f*(rci[4] + rnj) - acc[r][4]; o1.x = v; qs += v; q2s += v*v;
        v = 0.5f*(rci[5] + rnj) - acc[r][5]; o1.y = v; qs += v; q2s += v*v;
        v = 0.5f*(rci[6] + rnj) - acc[r][6]; o1.z = v; qs += v; q2s += v*v;
        v = 0.5f*(rci[7] + rnj) - acc[r][7]; o1.w = v; qs += v; q2s += v*v;
        *(float4*)(qm + rowp)     = o0;
        *(float4*)(qm + rowp + 4) = o1;
    }

    #pragma unroll
    for (int off = 32; off; off >>= 1) {
        qs  += __shfl_down(qs,  off);
        q2s += __shfl_down(q2s, off);
    }
    __shared__ float red[8];
    int wid = tid >> 6, lane = tid & 63;
    if (lane == 0) { red[wid] = qs; red[4 + wid] = q2s; }
    __syncthreads();
    if (tid == 0) {
        int tile = b * 32 + jt * 4 + it;
        qsums[tile]  = red[0] + red[1] + red[2] + red[3];
        q2sums[tile] = red[4] + red[5] + red[6] + red[7];
    }
}

// ---------------------------------------------------------------------------
__device__ __forceinline__ float gather16_sum_agent(const float* p)
{
    float acc = 0.f;
    #pragma unroll
    for (int g2 = 0; g2 < 16; ++g2)
        acc += __hip_atomic_load((float*)(p + g2 * SLOT), __ATOMIC_RELAXED,
                                 __HIP_MEMORY_SCOPE_AGENT);
    return acc;
}

// ---------------------------------------------------------------------------
// qp_iter_kernel v12: proven v10 structure; flag polls switched from
// ACQUIRE to RELAXED. Rationale: acquire agent-loads lower with an L2
// invalidate on gfx9xx; spinning with them trashes local L2 (counters:
// ~3.6 MB/round unexplained HBM re-fetch) and adds invalidate latency to
// every sync round. Correctness is unchanged: producer's RELEASE flag
// store pushes its part-stores to the coherence point first, and all
// consumer data reads are agent-scope atomic loads that bypass to the
// coherence point after a __syncthreads — the exact visibility argument
// the proven speculative-gather path already relies on.
// ---------------------------------------------------------------------------
__global__ __launch_bounds__(1024, 4) void qp_iter_kernel(
    const float* __restrict__ qm, const float* __restrict__ qsums,
    const float* __restrict__ q2sums, float* __restrict__ part,
    unsigned* __restrict__ flags, float* __restrict__ out)
{
    __shared__ float lds[16384 + 32];        // partial matrices + wred
    __shared__ int sh_ok;
    float* stage = lds;                      // [1024]: 0..511 f, 512..1023 colq
    float* wred  = lds + 16384;              // [16] wave partials for s

    int tid   = threadIdx.x;
    int blk   = blockIdx.x;
    int b     = blk >> 4;            // batch
    int g     = blk & 15;            // row-group: rows g*32..g*32+31
    int w     = tid >> 6;            // wave 0..15
    int lane  = tid & 63;
    int r_loc = tid >> 5;            // 0..31 local row
    int cseg  = tid & 31;            // owns cols cseg + 32k
    int j     = g * 32 + r_loc;

    size_t rowbase = ((size_t)b * NN + j) * MM;

    // ---- prologue: reduce 32 per-tile sums -> lr, s1 ----
    if (w == 0) {
        float v1 = (lane < 32) ? qsums[b * 32 + lane]  : 0.f;
        float v2 = (lane < 32) ? q2sums[b * 32 + lane] : 0.f;
        #pragma unroll
        for (int m = 32; m; m >>= 1) {
            v1 += __shfl_xor(v1, m);
            v2 += __shfl_xor(v2, m);
        }
        if (lane == 0) { wred[0] = v1; wred[1] = v2; }
    }

    float q[16], x[16], fk[16];
    #pragma unroll
    for (int k = 0; k < 16; ++k) q[k] = qm[rowbase + cseg + 32*k];

    const float inv_m = 1.0f / (float)MM;
    #pragma unroll
    for (int k = 0; k < 16; ++k) { x[k] = inv_m; fk[k] = 1.0f; }

    __syncthreads();
    const float lr = 0.5f / (wred[1] + 1e-8f);
    float s = wred[0] * inv_m;       // s1 = sum(qm)/m  (X0 = 1/m)

    unsigned* myflag = flags + b * 32 + g;
    unsigned* bflags = flags + b * 32;

    for (int t = 1; t <= QP_ITERS; ++t) {
        if (t > 1) {
            unsigned tt = (unsigned)(t - 1);
            // ---- speculative probe (relaxed; see header comment) ----
            if (w == 0) {
                unsigned v = (lane < 16)
                    ? __hip_atomic_load(bflags + lane, __ATOMIC_RELAXED,
                                        __HIP_MEMORY_SCOPE_AGENT)
                    : tt;
                int ok = __all(v >= tt);
                if (lane == 0) sh_ok = ok;
            }
            __syncthreads();   // broadcast sh_ok; prior lds reads all done

            const float* p = part + (size_t)((t - 1) & 1) * (NBLK * SLOT)
                           + (size_t)b * (16 * SLOT) + tid;
            float acc = gather16_sum_agent(p);

            if (!sh_ok) {      // fallback: relaxed poll + ordered re-gather
                if (w == 0) {
                    for (;;) {
                        unsigned v = (lane < 16)
                            ? __hip_atomic_load(bflags + lane, __ATOMIC_RELAXED,
                                                __HIP_MEMORY_SCOPE_AGENT)
                            : tt;
                        if (__all(v >= tt)) break;
                    }
                }
                __syncthreads();
                acc = gather16_sum_agent(p);
            }

            if (tid < 512) stage[tid] = fminf(1.0f, 2.0f / (acc + 1e-8f)); // f
            else           stage[tid] = acc;                               // colq
            __syncthreads();
            float v = (tid < 512) ? stage[tid] * stage[512 + tid] : 0.f;
            #pragma unroll
            for (int m = 32; m; m >>= 1) v += __shfl_xor(v, m);
            if (lane == 0) wred[w] = v;
            #pragma unroll
            for (int k = 0; k < 16; ++k) fk[k] = stage[cseg + 32*k];
            __syncthreads();   // wred ready; all stage reads complete
            float sacc = 0.f;
            #pragma unroll
            for (int i = 0; i < 16; ++i) sacc += wred[i];   // LDS broadcast
            s = sacc;
        }

        // ---- gradient step + clip + row normalize ----
        float c = 2.0f * lr * s;
        float rp = 0.f;
        #pragma unroll
        for (int k = 0; k < 16; ++k) {
            float v = x[k] * fk[k] - c * q[k];
            v = fminf(fmaxf(v, 0.f), 1.f);
            x[k] = v;
            rp += v;
        }
        #pragma unroll
        for (int m = 16; m; m >>= 1) rp += __shfl_xor(rp, m);
        float inv = 1.0f / (rp + 1e-8f);
        #pragma unroll
        for (int k = 0; k < 16; ++k) x[k] *= inv;

        // ---- column partial pass ----
        #pragma unroll
        for (int k = 0; k < 16; ++k) {
            float qx = q[k] * x[k];
            float px = x[k] + __shfl_xor(x[k], 32);   // row-pair sum
            float pq = qx   + __shfl_xor(qx,   32);
            int col = cseg + 32*k;
            if (lane < 32) lds[w * 512 + col]        = px;   // x partials
            else           lds[8192 + w * 512 + col] = pq;   // qx partials
        }
        __syncthreads();
        {
            int arr = tid >> 9;          // 0 => colsum(x), 1 => colsum(qx)
            int col = tid & 511;
            const float* basep = lds + arr * 8192 + col;
            float acc = 0.f;
            #pragma unroll
            for (int w2 = 0; w2 < 16; ++w2) acc += basep[w2 * 512];
            float* dst = part + (size_t)(t & 1) * (NBLK * SLOT)
                       + (size_t)blk * SLOT + tid;
            __hip_atomic_store(dst, acc, __ATOMIC_RELAXED,
                               __HIP_MEMORY_SCOPE_AGENT);
        }

        __syncthreads();   // drain every thread's partial store (vmcnt 0)
        if (tid == 0)
            __hip_atomic_store(myflag, (unsigned)t, __ATOMIC_RELEASE,
                               __HIP_MEMORY_SCOPE_AGENT);
    }

    // ---- final: poll iteration 20's flags, gather colsum, scale, store ----
    {
        unsigned tt = (unsigned)QP_ITERS;
        if (w == 0) {
            for (;;) {
                unsigned v = (lane < 16)
                    ? __hip_atomic_load(bflags + lane, __ATOMIC_RELAXED,
                                        __HIP_MEMORY_SCOPE_AGENT)
                    : tt;
                if (__all(v >= tt)) break;
            }
        }
        __syncthreads();
        const float* p = part + (size_t)(QP_ITERS & 1) * (NBLK * SLOT)
                       + (size_t)b * (16 * SLOT) + tid;   // tid<512: x-partials
        if (tid < 512) {
            float acc = gather16_sum_agent(p);
            stage[tid] = fminf(1.0f, 2.0f / (acc + 1e-8f));
        }
        __syncthreads();
        #pragma unroll
        for (int k = 0; k < 16; ++k)
            out[rowbase + cseg + 32*k] = x[k] * stage[cseg + 32*k];
    }
}

// ---------------------------------------------------------------------------
extern "C" void kernel_launch(void* const* d_in, const int* in_sizes, int n_in,
                              void* d_out, int out_size, void* d_ws, size_t ws_size,
                              hipStream_t stream)
{
    const float* nc = (const float*)d_in[0];  // n_emb_cur (16,512,128)
    const float* ec = (const float*)d_in[1];  // e_emb_cur
    const float* nn = (const float*)d_in[2];  // n_emb_nxt
    const float* en = (const float*)d_in[3];  // e_emb_nxt
    float* out = (float*)d_out;               // (16, 512*512) fp32

    float* ws = (float*)d_ws;
    const size_t QM_FLOATS = (size_t)BATCH * NN * MM;       // 4,194,304 (16 MB)

    float* qm   = ws;
    float* part = ws + QM_FLOATS;                           // 2*NBLK*SLOT floats
    float* qsums  = part + (size_t)2 * NBLK * SLOT;         // 512
    float* q2sums = qsums + 512;                            // 512
    unsigned* flags = (unsigned*)(q2sums + 512);            // 512 words

    gemm_q_kernel<<<dim3(4, 8, BATCH), 256, 0, stream>>>(nc, ec, nn, en, qm,
                                                         qsums, q2sums, flags);

    // NORMAL launch: capacity (2 blocks/CU x 256 CUs) >= 256 blocks ensures
    // co-residency; all inter-block sync is hand-rolled flag spins.
    qp_iter_kernel<<<dim3(NBLK), dim3(1024), 0, stream>>>(
        qm, qsums, q2sums, part, flags, out);
}

// Round 6
// 247.219 us; speedup vs baseline: 1.7795x; 1.0712x over previous
//
#include <hip/hip_runtime.h>

#define BATCH 16
#define NN 512   // n  (j index, "nxt" side; rows of X)
#define MM 512   // m  (i index, "cur" side; cols of X)
#define DD 128
#define QP_ITERS 20
#define NBLK (BATCH * 16)   // 256 qp blocks; 2-blocks/CU capacity => all resident
#define SLOT 1024           // floats per block slot (512 x-partials + 512 qx)

typedef __attribute__((ext_vector_type(8))) short bf16x8;   // 8 bf16 = 4 VGPR
typedef __attribute__((ext_vector_type(4))) float f32x4;    // MFMA C/D

#define LDR 56   // LDS row stride in bf16 units (112 B = 7*16: 16B-aligned rows,
                 // bank step 28 -> period-8 -> 2-way aliasing = free)

// ---------------------------------------------------------------------------
// gemm_q v6 (MFMA split-bf16): qm = 0.5*(rc_i + rn_j) - (nc.nn + ec.en).
// Gram matrices via mfma_f32_16x16x32_bf16 with hi/lo split (3 passes:
// hh + hl + lh; |err| ~ 2^-18 rel, ~100x below current absmax).
// Row norms still accumulated from the ORIGINAL fp32 values during staging.
// Correctness note: A and B fragments use identical LDS k-indexing, so any
// mis-assumption about the per-lane k-order is the same permutation on both
// operands and cancels in the dot product. Only the HW-verified C/D layout
// (col=lane&15, row=(lane>>4)*4+reg) is load-bearing.
// Tile: 128(i) x 64(j), 4 waves (2i x 2j), per-wave 64i x 32j = 8 frags.
// K-loop: 8 steps of 32 (2 matrices x 128d). Single-buffered LDS (43 KB).
// ---------------------------------------------------------------------------

__device__ __forceinline__ unsigned short bf16_rne(float f) {
    unsigned u = __float_as_uint(f);
    return (unsigned short)((u + 0x7FFFu + ((u >> 16) & 1u)) >> 16);
}

__device__ __forceinline__ void split4(float4 v, uint2& hi, uint2& lo) {
    unsigned short h0 = bf16_rne(v.x), h1 = bf16_rne(v.y),
                   h2 = bf16_rne(v.z), h3 = bf16_rne(v.w);
    hi.x = (unsigned)h0 | ((unsigned)h1 << 16);
    hi.y = (unsigned)h2 | ((unsigned)h3 << 16);
    unsigned short l0 = bf16_rne(v.x - __uint_as_float((unsigned)h0 << 16));
    unsigned short l1 = bf16_rne(v.y - __uint_as_float((unsigned)h1 << 16));
    unsigned short l2 = bf16_rne(v.z - __uint_as_float((unsigned)h2 << 16));
    unsigned short l3 = bf16_rne(v.w - __uint_as_float((unsigned)h3 << 16));
    lo.x = (unsigned)l0 | ((unsigned)l1 << 16);
    lo.y = (unsigned)l2 | ((unsigned)l3 << 16);
}

__device__ __forceinline__ float dot4(float4 v) {
    return v.x*v.x + v.y*v.y + v.z*v.z + v.w*v.w;
}

__global__ __launch_bounds__(256, 2) void gemm_q_kernel(
    const float* __restrict__ nc, const float* __restrict__ ec,
    const float* __restrict__ nn, const float* __restrict__ en,
    float* __restrict__ qm, float* __restrict__ qsums,
    float* __restrict__ q2sums, unsigned* __restrict__ flags)
{
    int b  = blockIdx.z;
    int it = blockIdx.x;             // i tile, 128 wide (0..3)
    int jt = blockIdx.y;             // j tile,  64 wide (0..7)
    int tid = threadIdx.x;

    if (it == 0 && jt == 0 && b == 0) {          // zero qp flags (512 words)
        flags[tid] = 0u; flags[tid + 256] = 0u;
    }

    __shared__ __align__(16) unsigned short sAh[64 * LDR];    // 7 KB
    __shared__ __align__(16) unsigned short sAl[64 * LDR];    // 7 KB
    __shared__ __align__(16) unsigned short sBh[128 * LDR];   // 14 KB
    __shared__ __align__(16) unsigned short sBl[128 * LDR];   // 14 KB

    int l  = tid & 63;
    int wv = tid >> 6;               // wave 0..3
    int wi = wv & 1;                 // i-half:   ibase = wi*64
    int wj = wv >> 1;                // j-half:   jbase = wj*32
    int lm = l & 15;                 // frag row/col index
    int lg = l >> 4;                 // frag k-group

    // staging coords: A 64 rows x 32k (8 fp32/thread), B 128 x 32 (16/thread)
    int ar  = tid >> 2, akq = (tid & 3) * 8;     // A row, k-offset {0,8,16,24}
    int br  = tid >> 1, bk0 = (tid & 1) * 16;    // B row, k-offset {0,16}

    const float* aBase[2] = { nn + ((size_t)b*NN + jt*64)  * DD,
                              en + ((size_t)b*NN + jt*64)  * DD };
    const float* bBase[2] = { nc + ((size_t)b*MM + it*128) * DD,
                              ec + ((size_t)b*MM + it*128) * DD };

    f32x4 acc[2][4];                 // [jf][if]
    #pragma unroll
    for (int a = 0; a < 2; ++a)
        #pragma unroll
        for (int c = 0; c < 4; ++c) acc[a][c] = (f32x4){0.f, 0.f, 0.f, 0.f};

    float s_a = 0.f, s_b = 0.f;      // fp32 row-norm partials

    for (int s = 0; s < 8; ++s) {
        const float* ga = aBase[s >> 2] + (size_t)ar * DD + (s & 3) * 32 + akq;
        const float* gb = bBase[s >> 2] + (size_t)br * DD + (s & 3) * 32 + bk0;
        float4 va0 = *(const float4*)(ga);
        float4 va1 = *(const float4*)(ga + 4);
        float4 vb0 = *(const float4*)(gb);
        float4 vb1 = *(const float4*)(gb + 4);
        float4 vb2 = *(const float4*)(gb + 8);
        float4 vb3 = *(const float4*)(gb + 12);
        s_a += dot4(va0) + dot4(va1);
        s_b += dot4(vb0) + dot4(vb1) + dot4(vb2) + dot4(vb3);

        __syncthreads();             // previous step's frag reads complete
        {
            uint2 h, lo;
            split4(va0, h, lo);
            *(uint2*)&sAh[ar*LDR + akq]     = h; *(uint2*)&sAl[ar*LDR + akq]     = lo;
            split4(va1, h, lo);
            *(uint2*)&sAh[ar*LDR + akq + 4] = h; *(uint2*)&sAl[ar*LDR + akq + 4] = lo;
            split4(vb0, h, lo);
            *(uint2*)&sBh[br*LDR + bk0]      = h; *(uint2*)&sBl[br*LDR + bk0]      = lo;
            split4(vb1, h, lo);
            *(uint2*)&sBh[br*LDR + bk0 + 4]  = h; *(uint2*)&sBl[br*LDR + bk0 + 4]  = lo;
            split4(vb2, h, lo);
            *(uint2*)&sBh[br*LDR + bk0 + 8]  = h; *(uint2*)&sBl[br*LDR + bk0 + 8]  = lo;
            split4(vb3, h, lo);
            *(uint2*)&sBh[br*LDR + bk0 + 12] = h; *(uint2*)&sBl[br*LDR + bk0 + 12] = lo;
        }
        __syncthreads();             // staged tile visible

        bf16x8 ah[2], al[2];
        #pragma unroll
        for (int jf = 0; jf < 2; ++jf) {
            int rr = wj*32 + jf*16 + lm;
            ah[jf] = *(const bf16x8*)&sAh[rr*LDR + lg*8];
            al[jf] = *(const bf16x8*)&sAl[rr*LDR + lg*8];
        }
        #pragma unroll
        for (int ff = 0; ff < 4; ++ff) {
            int rr = wi*64 + ff*16 + lm;
            bf16x8 bh = *(const bf16x8*)&sBh[rr*LDR + lg*8];
            bf16x8 bl = *(const bf16x8*)&sBl[rr*LDR + lg*8];
            #pragma unroll
            for (int jf = 0; jf < 2; ++jf) {
                acc[jf][ff] = __builtin_amdgcn_mfma_f32_16x16x32_bf16(
                                  ah[jf], bh, acc[jf][ff], 0, 0, 0);
                acc[jf][ff] = __builtin_amdgcn_mfma_f32_16x16x32_bf16(
                                  ah[jf], bl, acc[jf][ff], 0, 0, 0);
                acc[jf][ff] = __builtin_amdgcn_mfma_f32_16x16x32_bf16(
                                  al[jf], bh, acc[jf][ff], 0, 0, 0);
            }
        }
    }

    // ---- row-norm combine through reused LDS ----
    __syncthreads();                 // k-loop LDS reads complete
    float* nA = (float*)sAh;         // 256 floats: partials for A row j at 4j..4j+3
    float* nB = nA + 256;            // 256 floats: partials for B row i at 2i..2i+1
    nA[tid] = s_a;                   // tid == 4*ar + (tid&3)
    nB[tid] = s_b;                   // tid == 2*br + (tid&1)
    __syncthreads();

    float rci[4];
    #pragma unroll
    for (int ff = 0; ff < 4; ++ff) {
        int i_loc = wi*64 + ff*16 + lm;
        rci[ff] = nB[2*i_loc] + nB[2*i_loc + 1];   // ||nc_i||^2 + ||ec_i||^2
    }

    float qs = 0.f, q2s = 0.f;
    #pragma unroll
    for (int jf = 0; jf < 2; ++jf) {
        #pragma unroll
        for (int r = 0; r < 4; ++r) {
            int j_loc = wj*32 + jf*16 + lg*4 + r;   // C/D row = (lane>>4)*4+reg
            float rnj = nA[4*j_loc] + nA[4*j_loc+1]
                      + nA[4*j_loc+2] + nA[4*j_loc+3];
            size_t rowp = ((size_t)b*NN + jt*64 + j_loc) * MM + it*128;
            #pragma unroll
            for (int ff = 0; ff < 4; ++ff) {
                float v = 0.5f * (rci[ff] + rnj) - acc[jf][ff][r];
                qm[rowp + wi*64 + ff*16 + lm] = v;
                qs += v; q2s += v * v;
            }
        }
    }

    #pragma unroll
    for (int off = 32; off; off >>= 1) {
        qs  += __shfl_down(qs,  off);
        q2s += __shfl_down(q2s, off);
    }
    __shared__ float red[8];
    int lane = tid & 63;
    if (lane == 0) { red[wv] = qs; red[4 + wv] = q2s; }
    __syncthreads();
    if (tid == 0) {
        int tile = b * 32 + jt * 4 + it;
        qsums[tile]  = red[0] + red[1] + red[2] + red[3];
        q2sums[tile] = red[4] + red[5] + red[6] + red[7];
    }
}

// ---------------------------------------------------------------------------
__device__ __forceinline__ float gather16_sum_agent(const float* p)
{
    float acc = 0.f;
    #pragma unroll
    for (int g2 = 0; g2 < 16; ++g2)
        acc += __hip_atomic_load((float*)(p + g2 * SLOT), __ATOMIC_RELAXED,
                                 __HIP_MEMORY_SCOPE_AGENT);
    return acc;
}

// ---------------------------------------------------------------------------
// qp_iter_kernel v12 (R5-proven, 171 us, UNCHANGED): relaxed flag polls,
// release producer store, speculative probe + poll fallback.
// ---------------------------------------------------------------------------
__global__ __launch_bounds__(1024, 4) void qp_iter_kernel(
    const float* __restrict__ qm, const float* __restrict__ qsums,
    const float* __restrict__ q2sums, float* __restrict__ part,
    unsigned* __restrict__ flags, float* __restrict__ out)
{
    __shared__ float lds[16384 + 32];        // partial matrices + wred
    __shared__ int sh_ok;
    float* stage = lds;                      // [1024]: 0..511 f, 512..1023 colq
    float* wred  = lds + 16384;              // [16] wave partials for s

    int tid   = threadIdx.x;
    int blk   = blockIdx.x;
    int b     = blk >> 4;            // batch
    int g     = blk & 15;            // row-group: rows g*32..g*32+31
    int w     = tid >> 6;            // wave 0..15
    int lane  = tid & 63;
    int r_loc = tid >> 5;            // 0..31 local row
    int cseg  = tid & 31;            // owns cols cseg + 32k
    int j     = g * 32 + r_loc;

    size_t rowbase = ((size_t)b * NN + j) * MM;

    // ---- prologue: reduce 32 per-tile sums -> lr, s1 ----
    if (w == 0) {
        float v1 = (lane < 32) ? qsums[b * 32 + lane]  : 0.f;
        float v2 = (lane < 32) ? q2sums[b * 32 + lane] : 0.f;
        #pragma unroll
        for (int m = 32; m; m >>= 1) {
            v1 += __shfl_xor(v1, m);
            v2 += __shfl_xor(v2, m);
        }
        if (lane == 0) { wred[0] = v1; wred[1] = v2; }
    }

    float q[16], x[16], fk[16];
    #pragma unroll
    for (int k = 0; k < 16; ++k) q[k] = qm[rowbase + cseg + 32*k];

    const float inv_m = 1.0f / (float)MM;
    #pragma unroll
    for (int k = 0; k < 16; ++k) { x[k] = inv_m; fk[k] = 1.0f; }

    __syncthreads();
    const float lr = 0.5f / (wred[1] + 1e-8f);
    float s = wred[0] * inv_m;       // s1 = sum(qm)/m  (X0 = 1/m)

    unsigned* myflag = flags + b * 32 + g;
    unsigned* bflags = flags + b * 32;

    for (int t = 1; t <= QP_ITERS; ++t) {
        if (t > 1) {
            unsigned tt = (unsigned)(t - 1);
            // ---- speculative probe (relaxed) ----
            if (w == 0) {
                unsigned v = (lane < 16)
                    ? __hip_atomic_load(bflags + lane, __ATOMIC_RELAXED,
                                        __HIP_MEMORY_SCOPE_AGENT)
                    : tt;
                int ok = __all(v >= tt);
                if (lane == 0) sh_ok = ok;
            }
            __syncthreads();   // broadcast sh_ok; prior lds reads all done

            const float* p = part + (size_t)((t - 1) & 1) * (NBLK * SLOT)
                           + (size_t)b * (16 * SLOT) + tid;
            float acc = gather16_sum_agent(p);

            if (!sh_ok) {      // fallback: relaxed poll + ordered re-gather
                if (w == 0) {
                    for (;;) {
                        unsigned v = (lane < 16)
                            ? __hip_atomic_load(bflags + lane, __ATOMIC_RELAXED,
                                                __HIP_MEMORY_SCOPE_AGENT)
                            : tt;
                        if (__all(v >= tt)) break;
                    }
                }
                __syncthreads();
                acc = gather16_sum_agent(p);
            }

            if (tid < 512) stage[tid] = fminf(1.0f, 2.0f / (acc + 1e-8f)); // f
            else           stage[tid] = acc;                               // colq
            __syncthreads();
            float v = (tid < 512) ? stage[tid] * stage[512 + tid] : 0.f;
            #pragma unroll
            for (int m = 32; m; m >>= 1) v += __shfl_xor(v, m);
            if (lane == 0) wred[w] = v;
            #pragma unroll
            for (int k = 0; k < 16; ++k) fk[k] = stage[cseg + 32*k];
            __syncthreads();   // wred ready; all stage reads complete
            float sacc = 0.f;
            #pragma unroll
            for (int i = 0; i < 16; ++i) sacc += wred[i];   // LDS broadcast
            s = sacc;
        }

        // ---- gradient step + clip + row normalize ----
        float c = 2.0f * lr * s;
        float rp = 0.f;
        #pragma unroll
        for (int k = 0; k < 16; ++k) {
            float v = x[k] * fk[k] - c * q[k];
            v = fminf(fmaxf(v, 0.f), 1.f);
            x[k] = v;
            rp += v;
        }
        #pragma unroll
        for (int m = 16; m; m >>= 1) rp += __shfl_xor(rp, m);
        float inv = 1.0f / (rp + 1e-8f);
        #pragma unroll
        for (int k = 0; k < 16; ++k) x[k] *= inv;

        // ---- column partial pass ----
        #pragma unroll
        for (int k = 0; k < 16; ++k) {
            float qx = q[k] * x[k];
            float px = x[k] + __shfl_xor(x[k], 32);   // row-pair sum
            float pq = qx   + __shfl_xor(qx,   32);
            int col = cseg + 32*k;
            if (lane < 32) lds[w * 512 + col]        = px;   // x partials
            else           lds[8192 + w * 512 + col] = pq;   // qx partials
        }
        __syncthreads();
        {
            int arr = tid >> 9;          // 0 => colsum(x), 1 => colsum(qx)
            int col = tid & 511;
            const float* basep = lds + arr * 8192 + col;
            float acc = 0.f;
            #pragma unroll
            for (int w2 = 0; w2 < 16; ++w2) acc += basep[w2 * 512];
            float* dst = part + (size_t)(t & 1) * (NBLK * SLOT)
                       + (size_t)blk * SLOT + tid;
            __hip_atomic_store(dst, acc, __ATOMIC_RELAXED,
                               __HIP_MEMORY_SCOPE_AGENT);
        }

        __syncthreads();   // drain every thread's partial store (vmcnt 0)
        if (tid == 0)
            __hip_atomic_store(myflag, (unsigned)t, __ATOMIC_RELEASE,
                               __HIP_MEMORY_SCOPE_AGENT);
    }

    // ---- final: poll iteration 20's flags, gather colsum, scale, store ----
    {
        unsigned tt = (unsigned)QP_ITERS;
        if (w == 0) {
            for (;;) {
                unsigned v = (lane < 16)
                    ? __hip_atomic_load(bflags + lane, __ATOMIC_RELAXED,
                                        __HIP_MEMORY_SCOPE_AGENT)
                    : tt;
                if (__all(v >= tt)) break;
            }
        }
        __syncthreads();
        const float* p = part + (size_t)(QP_ITERS & 1) * (NBLK * SLOT)
                       + (size_t)b * (16 * SLOT) + tid;   // tid<512: x-partials
        if (tid < 512) {
            float acc = gather16_sum_agent(p);
            stage[tid] = fminf(1.0f, 2.0f / (acc + 1e-8f));
        }
        __syncthreads();
        #pragma unroll
        for (int k = 0; k < 16; ++k)
            out[rowbase + cseg + 32*k] = x[k] * stage[cseg + 32*k];
    }
}

// ---------------------------------------------------------------------------
extern "C" void kernel_launch(void* const* d_in, const int* in_sizes, int n_in,
                              void* d_out, int out_size, void* d_ws, size_t ws_size,
                              hipStream_t stream)
{
    const float* nc = (const float*)d_in[0];  // n_emb_cur (16,512,128)
    const float* ec = (const float*)d_in[1];  // e_emb_cur
    const float* nn = (const float*)d_in[2];  // n_emb_nxt
    const float* en = (const float*)d_in[3];  // e_emb_nxt
    float* out = (float*)d_out;               // (16, 512*512) fp32

    float* ws = (float*)d_ws;
    const size_t QM_FLOATS = (size_t)BATCH * NN * MM;       // 4,194,304 (16 MB)

    float* qm   = ws;
    float* part = ws + QM_FLOATS;                           // 2*NBLK*SLOT floats
    float* qsums  = part + (size_t)2 * NBLK * SLOT;         // 512
    float* q2sums = qsums + 512;                            // 512
    unsigned* flags = (unsigned*)(q2sums + 512);            // 512 words

    gemm_q_kernel<<<dim3(4, 8, BATCH), 256, 0, stream>>>(nc, ec, nn, en, qm,
                                                         qsums, q2sums, flags);

    // NORMAL launch: capacity (2 blocks/CU x 256 CUs) >= 256 blocks ensures
    // co-residency; all inter-block sync is hand-rolled flag spins.
    qp_iter_kernel<<<dim3(NBLK), dim3(1024), 0, stream>>>(
        qm, qsums, q2sums, part, flags, out);
}